// Round 8
// baseline (273.495 us; speedup 1.0000x reference)
//
#include <hip/hip_runtime.h>
#include <math.h>

// Problem constants (from reference)
#define NH 4
#define HD 64
#define HIDDEN 256
#define BS 32
#define NB 64          // NUM_BLOCKS = MAX_LEN/BS = 2048/32
#define SCALE 0.125f
#define INV_SCALE 8.0f

__device__ __forceinline__ float fast_sigmoid(float x) {
    return 1.0f / (1.0f + __expf(-x));
}
__device__ __forceinline__ float readlane_f(float v, int lane) {
    return __int_as_float(__builtin_amdgcn_readlane(__float_as_int(v), lane));
}
__device__ __forceinline__ unsigned long long umax64(unsigned long long a, unsigned long long b) {
    return a > b ? a : b;
}
__device__ __forceinline__ unsigned long long umin64(unsigned long long a, unsigned long long b) {
    return a < b ? a : b;
}

// Kernel 1 (unchanged from R7): block means. K in f64 (selection path must be
// f64-exact vs the np reference), V in f32. Paired layouts:
// k_cmp2 (double): [b][h][dd2][m][par]  -> lane-d double2 = (2dd2,2dd2+1) at m=d
// v_cmp2 (float) : [b][h][m2][d][par]   -> lane-d float2  = (2m2,2m2+1) at d
__global__ __launch_bounds__(256) void kcmp_kernel(
    const float* __restrict__ k, const float* __restrict__ v,
    const int* __restrict__ x_offsets,
    double* __restrict__ k_cmp2, float* __restrict__ v_cmp2) {
    int bb  = blockIdx.x;          // b*NB + blk
    int b   = bb >> 6;
    int blk = bb & 63;
    int tid = threadIdx.x;         // column: h = tid>>6, d = tid&63
    int s0   = x_offsets[b];
    int len  = x_offsets[b + 1] - s0;
    int nblk = len >> 5;
    int h = tid >> 6, d = tid & 63;
    if (blockIdx.y == 0) {
        double acc = 0.0;
        if (blk < nblk) {
            const float* kp = k + (size_t)(s0 + blk * BS) * HIDDEN + tid;
            #pragma unroll
            for (int i = 0; i < BS; ++i) acc += (double)kp[i * HIDDEN];
            acc *= (1.0 / BS);
        }
        k_cmp2[((size_t)(b * NH + h) * 32 + (d >> 1)) * 128 + blk * 2 + (d & 1)] = acc;
    } else {
        float acc = 0.f;
        if (blk < nblk) {
            const float* vp = v + (size_t)(s0 + blk * BS) * HIDDEN + tid;
            #pragma unroll
            for (int i = 0; i < BS; ++i) acc += vp[i * HIDDEN];
            acc *= (1.0f / BS);
        }
        v_cmp2[((size_t)(b * NH + h) * 32 + (blk >> 1)) * 128 + d * 2 + (blk & 1)] = acc;
    }
}

// Kernel 2: one workgroup (256 threads = 4 waves) per token t. Wave h = head h.
__global__ __launch_bounds__(256, 8) void hstu_main_kernel(
    const float* __restrict__ q, const float* __restrict__ k,
    const float* __restrict__ v, const float* __restrict__ u,
    const float* __restrict__ Wg_cmp,
    const int* __restrict__ x_offsets, const int* __restrict__ batch_ids,
    const int* __restrict__ pos_ids,
    const double* __restrict__ k_cmp2, const float* __restrict__ v_cmp2,
    float* __restrict__ out, int T) {
    int t   = blockIdx.x;
    int tid = threadIdx.x;
    int h = __builtin_amdgcn_readfirstlane(tid >> 6);  // wave-uniform -> SGPR
    int d = tid & 63;
    int b    = batch_ids[t];      // t uniform -> scalar loads
    int pos  = pos_ids[t];
    int s0   = x_offsets[b];
    int qblk = pos >> 5;

    const float* qrow = q + (size_t)t * HIDDEN + h * HD;  // uniform base -> s_load
    float qv = qrow[d];

    // g = sigmoid(q[h] . Wg_cmp[h])  (wave reduction; overlaps kc2 load latency)
    float gsum = qv * Wg_cmp[h * HD + d];
    #pragma unroll
    for (int off = 32; off; off >>= 1) gsum += __shfl_xor(gsum, off, 64);
    float g = fast_sigmoid(gsum);

    // ---- Compressed scores in f64 (selection must be tie-exact vs np ref) ----
    const double2* kc2 = (const double2*)k_cmp2 + (size_t)(b * NH + h) * 32 * 64 + d;
    double raw = 0.0;
    #pragma unroll 16
    for (int dd2 = 0; dd2 < 32; ++dd2) {
        double2 kk = kc2[dd2 * 64];
        raw += (double)qrow[2 * dd2] * kk.x + (double)qrow[2 * dd2 + 1] * kk.y;
    }
    raw *= 0.125;
    double p64 = 0.0;
    if (d <= qblk) p64 = raw / (1.0 + exp(-raw)) * 8.0;   // silu(raw)*INV_SCALE
    double sel = (d == qblk) ? 1.0 : p64;
    float p = (float)p64;   // exactly 0 for lanes > qblk

    // Monotone u64 key; index packed in low 6 mantissa bits (ambiguity < 2^-46).
    long long sbits = __double_as_longlong(sel);
    unsigned long long mykey = (unsigned long long)sbits;
    mykey = (sbits < 0) ? ~mykey : (mykey | 0x8000000000000000ull);
    mykey = (mykey & ~63ull) | (unsigned long long)(63 - d);

    // ---- o_cmp BEFORE top-k: its loads fly during the shuffle chain ----
    const float2* vc2 = (const float2*)v_cmp2 + (size_t)(b * NH + h) * 32 * 64 + d;
    float oc = 0.f;
    int mp2 = ((qblk >> 1) + 8) & ~7;              // 8,16,24,32 pairs; covers qblk
    #pragma unroll 8
    for (int m2 = 0; m2 < mp2; ++m2) {
        float2 vv = vc2[m2 * 64];
        oc += readlane_f(p, 2 * m2) * vv.x + readlane_f(p, 2 * m2 + 1) * vv.y;
    }
    oc *= g;

    // ---- top-3 in ONE butterfly: carry sorted triple (a0>=a1>=a2) ----
    unsigned long long a0 = mykey, a1 = 0ull, a2 = 0ull;
    #pragma unroll
    for (int off = 32; off; off >>= 1) {
        unsigned long long b0 = __shfl_xor(a0, off, 64);
        unsigned long long b1 = __shfl_xor(a1, off, 64);
        unsigned long long b2 = __shfl_xor(a2, off, 64);
        unsigned long long M00 = umax64(a0, b0), m01 = umin64(a0, b0);
        unsigned long long M11 = umax64(a1, b1);
        unsigned long long M22 = umax64(a2, b2);
        a0 = M00;
        a1 = umax64(m01, M11);
        a2 = umax64(umin64(m01, M11), M22);
    }
    int idx0 = __builtin_amdgcn_readfirstlane(63 - (int)(a0 & 63ull));
    int idx2 = __builtin_amdgcn_readfirstlane(63 - (int)(a2 & 63ull));

    // ---- o_slc scores, coalesced: lane=(c,r); 4 its x 16 rows; pl kept in
    // registers (replicated across c-groups after the reduction) ----
    int r = d & 15, c = d >> 4;
    float4 qf[4];
    {
        const float4* q4 = (const float4*)qrow;
        #pragma unroll
        for (int j = 0; j < 4; ++j) qf[j] = q4[c + 4 * j];
    }
    float pl[4];
    #pragma unroll
    for (int it = 0; it < 4; ++it) {
        int blk_l = (it >= 2) ? idx2 : idx0;       // scalar
        int ii    = (it & 1) * 16 + r;
        int pis   = blk_l * BS + ii;
        int tgt   = s0 + pis;
        if (tgt > T - 1) tgt = T - 1;
        const float4* kr = (const float4*)(k + (size_t)tgt * HIDDEN + h * HD) + c;
        float ps = 0.f;
        #pragma unroll
        for (int j = 0; j < 4; ++j) {
            float4 kk = kr[j * 4];
            ps += qf[j].x * kk.x + qf[j].y * kk.y + qf[j].z * kk.z + qf[j].w * kk.w;
        }
        ps += __shfl_xor(ps, 16, 64);
        ps += __shfl_xor(ps, 32, 64);              // now replicated across c
        float scv = ps * SCALE;
        pl[it] = (pis <= pos) ? scv * fast_sigmoid(scv) * (INV_SCALE * 2.0f) : 0.f;
    }

    // ---- o_slc accumulate: fixed 2x32 fully-unrolled, coalesced V rows.
    // pl broadcasts are 0 beyond pos / for invalid blocks; substitute block 0
    // when idx2 is invalid so addresses stay in-sequence (products are 0). ----
    float os = 0.f;
    int bsafe1 = (idx2 > qblk) ? 0 : idx2;
    const float* vr0 = v + (size_t)(s0 + idx0  * BS) * HIDDEN + h * HD + d;
    const float* vr1 = v + (size_t)(s0 + bsafe1 * BS) * HIDDEN + h * HD + d;
    #pragma unroll
    for (int i = 0; i < BS; ++i) {
        // row i of block0: pl[i>>4] at lane (i&15); row i of block1: pl[2+(i>>4)]
        os += readlane_f(pl[i >> 4], i & 15) * vr0[i * HIDDEN];
        os += readlane_f(pl[2 + (i >> 4)], i & 15) * vr1[i * HIDDEN];
    }

    // ---- dual LayerNorm over 256 dims + gate by u, sum ----
    __shared__ float red[NH][4];
    float sc_ = oc, sc2 = oc * oc, ss_ = os, ss2 = os * os;
    #pragma unroll
    for (int off = 32; off; off >>= 1) {
        sc_ += __shfl_xor(sc_, off, 64);
        sc2 += __shfl_xor(sc2, off, 64);
        ss_ += __shfl_xor(ss_, off, 64);
        ss2 += __shfl_xor(ss2, off, 64);
    }
    if (d == 0) { red[h][0] = sc_; red[h][1] = sc2; red[h][2] = ss_; red[h][3] = ss2; }
    __syncthreads();
    float tc = 0.f, tc2 = 0.f, ts = 0.f, ts2 = 0.f;
    #pragma unroll
    for (int w = 0; w < NH; ++w) {
        tc += red[w][0]; tc2 += red[w][1]; ts += red[w][2]; ts2 += red[w][3];
    }
    float muc  = tc  * (1.0f / HIDDEN);
    float varc = tc2 * (1.0f / HIDDEN) - muc * muc;
    float mus  = ts  * (1.0f / HIDDEN);
    float vars = ts2 * (1.0f / HIDDEN) - mus * mus;
    float uval = u[(size_t)t * HIDDEN + tid];
    float outv = (oc - muc) * rsqrtf(varc + 1e-6f) * uval
               + (os - mus) * rsqrtf(vars + 1e-6f) * uval;
    out[(size_t)t * HIDDEN + tid] = outv;
}

extern "C" void kernel_launch(void* const* d_in, const int* in_sizes, int n_in,
                              void* d_out, int out_size, void* d_ws, size_t ws_size,
                              hipStream_t stream) {
    const float* q      = (const float*)d_in[0];
    const float* k      = (const float*)d_in[1];
    const float* v      = (const float*)d_in[2];
    const float* u      = (const float*)d_in[3];
    const float* Wg_cmp = (const float*)d_in[4];
    // d_in[5] = Wg_slc: dead code in the reference (computed, never used)
    const int* x_offsets = (const int*)d_in[6];
    const int* batch_ids = (const int*)d_in[7];
    const int* pos_ids   = (const int*)d_in[8];

    int T = in_sizes[0] / HIDDEN;
    int B = in_sizes[6] - 1;

    double* k_cmp2 = (double*)d_ws;                       // B*NH*HD*NB doubles (1 MB)
    float*  v_cmp2 = (float*)(k_cmp2 + (size_t)B * NH * HD * NB);  // B*NH*NB*HD floats

    kcmp_kernel<<<dim3(B * NB, 2), 256, 0, stream>>>(k, v, x_offsets, k_cmp2, v_cmp2);
    hstu_main_kernel<<<T, 256, 0, stream>>>(q, k, v, u, Wg_cmp,
                                            x_offsets, batch_ids, pos_ids,
                                            k_cmp2, v_cmp2, (float*)d_out, T);
}